// Round 6
// baseline (2232.009 us; speedup 1.0000x reference)
//
#include <hip/hip_runtime.h>
#include <stdint.h>

#define B_ 64
#define T_ 512
#define I_ 128
#define H_ 512
#define O_ 64
#define ALPHA_ 0.1f

// K-split recurrence geometry: 8 waves, wave w owns h-pair slice [32w,32w+32).
// Lane l computes rows {64j + l}, j=0..7. 256 weight pairs/lane:
//   CV=22 c's resident in VGPRs (176), CS=10 c's streamed from L2 (80).
#define CV 22
#define CS 10
#define R_END (176 * 512)          // wrecR dwords
#define S_END (R_END + 80 * 512)   // + wrecS dwords
#define WIN_END (S_END + 512 * 64)

typedef _Float16 f16;
typedef _Float16 f16x2 __attribute__((ext_vector_type(2)));

__device__ __forceinline__ uint32_t pkf16(float a, float b) {
  f16 ha = (f16)a, hb = (f16)b;
  uint16_t ua = __builtin_bit_cast(uint16_t, ha);
  uint16_t ub = __builtin_bit_cast(uint16_t, hb);
  return (uint32_t)ua | ((uint32_t)ub << 16);
}

__device__ __forceinline__ float dot2(uint32_t w, uint32_t h, float acc) {
#if __has_builtin(__builtin_amdgcn_fdot2)
  return __builtin_amdgcn_fdot2(__builtin_bit_cast(f16x2, w),
                                __builtin_bit_cast(f16x2, h), acc, false);
#else
  f16x2 wv = __builtin_bit_cast(f16x2, w), hv = __builtin_bit_cast(f16x2, h);
  return acc + (float)wv[0] * (float)hv[0] + (float)wv[1] * (float)hv[1];
#endif
}

__device__ __forceinline__ float tanhfast(float x) {
  float e = __expf(2.0f * x);   // inf-safe at both ends
#if __has_builtin(__builtin_amdgcn_rcpf)
  return 1.0f - 2.0f * __builtin_amdgcn_rcpf(e + 1.0f);
#else
  return 1.0f - 2.0f / (e + 1.0f);
#endif
}

// ---------------------------------------------------------------------------
// Pack weights (f16x2 pairs):
//  wrecR[(j*CV+c)*512 + t]        = W_rec[64j+(t&63)][64(t>>6)+2c ..+1], c<CV
//  wrecS[g*2048 + t*4 + q]        : idx70=g*4+q, j=idx70/10, cc=idx70%10,
//                                   = W_rec[64j+(t&63)][64(t>>6)+2(CV+cc)..+1]
//    (per-lane contiguous 16B quads -> coalesced dwordx4 streaming loads)
//  winT [k*512 + n] = W_in[n][2k..+1]
//  woutT[k*64  + o] = W_out[o][2k..+1]
// ---------------------------------------------------------------------------
__global__ __launch_bounds__(256) void pack_w(
    const float* __restrict__ Wrec, const float* __restrict__ Win,
    const float* __restrict__ Wout, uint32_t* __restrict__ wrecR,
    uint32_t* __restrict__ wrecS, uint32_t* __restrict__ winT,
    uint32_t* __restrict__ woutT) {
  int id = blockIdx.x * 256 + threadIdx.x;
  if (id < R_END) {
    int cj = id >> 9, t = id & 511;
    int j = cj / CV, c = cj % CV;
    int row = 64 * j + (t & 63), col = 64 * (t >> 6) + 2 * c;
    const float* s = Wrec + row * 512 + col;
    wrecR[id] = pkf16(s[0], s[1]);
  } else if (id < S_END) {
    int e = id - R_END;
    int g = e >> 11, rem = e & 2047, t = rem >> 2, q = rem & 3;
    int i70 = g * 4 + q, j = i70 / CS, cc = i70 % CS;
    int row = 64 * j + (t & 63), col = 64 * (t >> 6) + 2 * (CV + cc);
    const float* s = Wrec + row * 512 + col;
    wrecS[e] = pkf16(s[0], s[1]);
  } else if (id < WIN_END) {
    int e = id - S_END;
    int n = e >> 6, k = e & 63;
    const float* s = Win + n * 128 + 2 * k;
    winT[k * 512 + n] = pkf16(s[0], s[1]);
  } else {
    int e = id - WIN_END;
    int o = e >> 8, k = e & 255;
    const float* s = Wout + o * 512 + 2 * k;
    woutT[k * 64 + o] = pkf16(s[0], s[1]);
  }
}

// ---------------------------------------------------------------------------
// x_proj: xp[m, n] = sum_i inputs[m, i] * W_in[n, i]   (m = b*T+ts, f16 out)
// ---------------------------------------------------------------------------
__global__ __launch_bounds__(512) void xproj_k(
    const float* __restrict__ in, const uint32_t* __restrict__ winT,
    f16* __restrict__ xp) {
  __shared__ uint32_t A[32][64];
  const int t = threadIdx.x;
  const int m0 = blockIdx.x * 32;
#pragma unroll
  for (int i = 0; i < 4; i++) {
    int id = i * 512 + t;
    int r = id >> 6, k = id & 63;
    const float* s = in + (m0 + r) * I_ + 2 * k;
    A[r][k] = pkf16(s[0], s[1]);
  }
  uint32_t w[64];
#pragma unroll
  for (int k = 0; k < 64; k++) w[k] = winT[k * 512 + t];
  __syncthreads();
  for (int r = 0; r < 32; r++) {
    float a0 = 0.f, a1 = 0.f, a2 = 0.f, a3 = 0.f;
#pragma unroll
    for (int k4 = 0; k4 < 16; k4++) {
      uint4 hq = *((const uint4*)&A[r][k4 * 4]);
      a0 = dot2(w[4 * k4 + 0], hq.x, a0);
      a1 = dot2(w[4 * k4 + 1], hq.y, a1);
      a2 = dot2(w[4 * k4 + 2], hq.z, a2);
      a3 = dot2(w[4 * k4 + 3], hq.w, a3);
    }
    xp[(m0 + r) * H_ + t] = (f16)((a0 + a1) + (a2 + a3));
  }
}

// ---------------------------------------------------------------------------
// Recurrence, K-split: one WG per batch row, 512 threads / 8 waves.
// Wave w = k-slice [32w,32w+32) pairs; lane l partial-dots rows {64j+l}.
// Per step: 8 uniform LDS h-quads per wave (vs 64 before), partials reduced
// through pld[8][512] (stride-4B conflict-free), 2 barriers (lgkm-only
// drains; vm stays in flight). 80 weight pairs/lane streamed from L2 each
// step in 2 reg-reused chunks; sched_barrier(0) fences keep the chunks'
// live ranges disjoint (spill protection).
// ---------------------------------------------------------------------------
__global__ __attribute__((amdgpu_flat_work_group_size(512, 512),
                          amdgpu_waves_per_eu(2, 2)))
void rnn_k(const uint32_t* __restrict__ wrecR, const uint32_t* __restrict__ wrecS,
           const f16* __restrict__ xp, const float* __restrict__ bias,
           const float* __restrict__ h0, f16* __restrict__ hall,
           float* __restrict__ hfin) {
  __shared__ uint32_t hbuf[512];   // 2 x 256 f16x2 pairs (double-buffered h)
  __shared__ float pld[8 * 512];   // partials [slice][row], 16 KB
  const int b = blockIdx.x, t = threadIdx.x;
  const int l = t & 63, wv = t >> 6;

  uint32_t wr[8][CV];  // 176 resident weight pairs
#pragma unroll
  for (int j = 0; j < 8; j++)
#pragma unroll
    for (int c = 0; c < CV; c++) wr[j][c] = wrecR[(j * CV + c) * 512 + t];

  float hv = h0[b * H_ + t];
  const float bia = bias[t];
  ((f16*)hbuf)[t] = (f16)hv;

  const f16* xpp = xp + b * (T_ * H_) + t;
  f16* hap = hall + b * H_ + t;
  const uint4* sQ = (const uint4*)wrecS;
  float xv = (float)xpp[0];
  __syncthreads();

  for (int ts = 0; ts < T_; ++ts) {
    // ---- issue streamed chunk S0 (j 0..3, c CV..CV+9) ----
    uint32_t s0v[40];
#pragma unroll
    for (int g = 0; g < 10; g++) {
      uint4 v = sQ[g * 512 + t];
      s0v[4 * g + 0] = v.x; s0v[4 * g + 1] = v.y;
      s0v[4 * g + 2] = v.z; s0v[4 * g + 3] = v.w;
    }
    __builtin_amdgcn_sched_barrier(0);
    // ---- resident compute on this wave's h-slice (8 uniform quads) ----
    const uint32_t* hb = hbuf + ((ts & 1) << 8) + (wv << 5);
    float acc[8];
#pragma unroll
    for (int j = 0; j < 8; j++) acc[j] = 0.f;
#pragma unroll
    for (int qd = 0; qd < 5; qd++) {
      uint4 q = *((const uint4*)(hb + 4 * qd));
      uint32_t qa[4] = {q.x, q.y, q.z, q.w};
#pragma unroll
      for (int cc = 0; cc < 4; cc++)
#pragma unroll
        for (int j = 0; j < 8; j++)
          acc[j] = dot2(wr[j][qd * 4 + cc], qa[cc], acc[j]);
    }
    uint4 q5 = *((const uint4*)(hb + 20));
    uint4 q6 = *((const uint4*)(hb + 24));
    uint4 q7 = *((const uint4*)(hb + 28));
#pragma unroll
    for (int j = 0; j < 8; j++) {
      acc[j] = dot2(wr[j][20], q5.x, acc[j]);
      acc[j] = dot2(wr[j][21], q5.y, acc[j]);
    }
    uint32_t hs[10] = {q5.z, q5.w, q6.x, q6.y, q6.z,
                       q6.w, q7.x, q7.y, q7.z, q7.w};
    // ---- consume S0 ----
#pragma unroll
    for (int j = 0; j < 4; j++)
#pragma unroll
      for (int cc = 0; cc < CS; cc++)
        acc[j] = dot2(s0v[j * CS + cc], hs[cc], acc[j]);
    __builtin_amdgcn_sched_barrier(0);
    // ---- issue streamed chunk S1 (j 4..7) into reused registers ----
    uint32_t s1v[40];
#pragma unroll
    for (int g = 0; g < 10; g++) {
      uint4 v = sQ[(10 + g) * 512 + t];
      s1v[4 * g + 0] = v.x; s1v[4 * g + 1] = v.y;
      s1v[4 * g + 2] = v.z; s1v[4 * g + 3] = v.w;
    }
    __builtin_amdgcn_sched_barrier(0);
    // ---- early partial writes (j 0..3) help cover S1 latency ----
#pragma unroll
    for (int j = 0; j < 4; j++) pld[(wv << 9) + (j << 6) + l] = acc[j];
    // ---- consume S1 ----
#pragma unroll
    for (int j = 4; j < 8; j++)
#pragma unroll
      for (int cc = 0; cc < CS; cc++)
        acc[j] = dot2(s1v[(j - 4) * CS + cc], hs[cc], acc[j]);
#pragma unroll
    for (int j = 4; j < 8; j++) pld[(wv << 9) + (j << 6) + l] = acc[j];
    // xp prefetch for next step (vm, stays in flight across barriers)
    float xn = 0.f;
    if (ts + 1 < T_) xn = (float)xpp[(ts + 1) * H_];
    asm volatile("s_waitcnt lgkmcnt(0)" ::: "memory");
    __builtin_amdgcn_s_barrier();
    asm volatile("" ::: "memory");
    // ---- reduce: thread t owns row t ----
    float sum = 0.f;
#pragma unroll
    for (int w8 = 0; w8 < 8; w8++) sum += pld[(w8 << 9) + t];
    float pre = sum + bia + xv;
    hv = (1.0f - ALPHA_) * hv + ALPHA_ * tanhfast(pre);
    f16 hh = (f16)hv;
    ((f16*)hbuf)[(((ts + 1) & 1) << 9) + t] = hh;
    hap[ts * (B_ * H_)] = hh;
    xv = xn;
    asm volatile("s_waitcnt lgkmcnt(0)" ::: "memory");
    __builtin_amdgcn_s_barrier();
    asm volatile("" ::: "memory");
  }
  hfin[b * H_ + t] = hv;
}

// ---------------------------------------------------------------------------
// out[b, ts, o] = sum_h hall[ts][b][h] * W_out[o, h] + b_out[o]
// ---------------------------------------------------------------------------
__global__ __launch_bounds__(256) void outgemm_k(
    const f16* __restrict__ hall, const uint32_t* __restrict__ woutT,
    const float* __restrict__ bout, float* __restrict__ out) {
  __shared__ uint32_t A[32][256];
  const int bid = blockIdx.x;
  const int b = bid >> 4, ts0 = (bid & 15) * 32;
  const int t = threadIdx.x, o = t & 63, g = t >> 6;
  const uint32_t* hp = (const uint32_t*)hall;
#pragma unroll
  for (int i = 0; i < 32; i++) {
    int id = i * 256 + t;
    int r = id >> 8, k = id & 255;
    A[r][k] = hp[(ts0 + r) * (B_ * H_ / 2) + b * (H_ / 2) + k];
  }
  const float bo = bout[o];
  __syncthreads();
  float acc[8];
#pragma unroll
  for (int r = 0; r < 8; r++) acc[r] = 0.f;
  for (int k4 = 0; k4 < 64; k4++) {
    uint32_t w0 = woutT[(4 * k4 + 0) * 64 + o];
    uint32_t w1 = woutT[(4 * k4 + 1) * 64 + o];
    uint32_t w2 = woutT[(4 * k4 + 2) * 64 + o];
    uint32_t w3 = woutT[(4 * k4 + 3) * 64 + o];
#pragma unroll
    for (int r = 0; r < 8; r++) {
      uint4 hq = *((const uint4*)&A[g * 8 + r][k4 * 4]);
      acc[r] = dot2(w0, hq.x, acc[r]);
      acc[r] = dot2(w1, hq.y, acc[r]);
      acc[r] = dot2(w2, hq.z, acc[r]);
      acc[r] = dot2(w3, hq.w, acc[r]);
    }
  }
#pragma unroll
  for (int r = 0; r < 8; r++)
    out[(b * T_ + ts0 + g * 8 + r) * O_ + o] = acc[r] + bo;
}

extern "C" void kernel_launch(void* const* d_in, const int* in_sizes, int n_in,
                              void* d_out, int out_size, void* d_ws,
                              size_t ws_size, hipStream_t stream) {
  const float* inputs = (const float*)d_in[0];  // [B,T,I]
  const float* h0     = (const float*)d_in[1];  // [B,H]
  const float* Win    = (const float*)d_in[2];  // [H,I]
  const float* Wrec   = (const float*)d_in[3];  // [H,H]
  const float* bias   = (const float*)d_in[4];  // [H]
  const float* Wout   = (const float*)d_in[5];  // [O,H]
  const float* bout   = (const float*)d_in[6];  // [O]
  float* out = (float*)d_out;                   // [B,T,O] then [B,H]

  uint8_t* ws = (uint8_t*)d_ws;
  uint32_t* wrecR = (uint32_t*)(ws);                      // 352 KB
  uint32_t* wrecS = (uint32_t*)(ws + (384u << 10));       // 160 KB
  uint32_t* winT  = (uint32_t*)(ws + (576u << 10));       // 128 KB
  uint32_t* woutT = (uint32_t*)(ws + (704u << 10));       //  64 KB
  f16* xp   = (f16*)(ws + (1u << 20));                    //  32 MB [B,T,H]
  f16* hall = (f16*)(ws + (1u << 20) + (32u << 20));      //  32 MB [T,B,H]

  hipLaunchKernelGGL(pack_w, dim3(704), dim3(256), 0, stream, Wrec, Win, Wout,
                     wrecR, wrecS, winT, woutT);
  hipLaunchKernelGGL(xproj_k, dim3(32768 / 32), dim3(512), 0, stream, inputs,
                     winT, xp);
  hipLaunchKernelGGL(rnn_k, dim3(B_), dim3(512), 0, stream, wrecR, wrecS, xp,
                     bias, h0, hall, out + B_ * T_ * O_);
  hipLaunchKernelGGL(outgemm_k, dim3(B_ * (T_ / 32)), dim3(256), 0, stream,
                     hall, woutT, bout, out);
}

// Round 7
// 1710.924 us; speedup vs baseline: 1.3046x; 1.3046x over previous
//
#include <hip/hip_runtime.h>
#include <stdint.h>

#define B_ 64
#define T_ 512
#define I_ 128
#define H_ 512
#define O_ 64
#define ALPHA_ 0.1f

// K-split recurrence: 8 waves, wave w owns h-pair slice [32w,32w+32).
// Lane l computes rows {64j+l}, j=0..7 (8 partial dots over 32 pairs).
// Weight pairs per lane: 256 total = CV*8 resident in VGPRs + 4 streamed
// chunks of 32 (8 x dwordx4, double-buffered sva/svb -> peak 2 chunks live).
#define CV 16
#define R_DW (128 * 512)          // wrecR dwords (j,c resident)
#define S_END (R_DW + 128 * 512)  // + wrecS dwords (streamed quads)
#define WIN_END (S_END + 512 * 64)

typedef _Float16 f16;
typedef _Float16 f16x2 __attribute__((ext_vector_type(2)));

__device__ __forceinline__ uint32_t pkf16(float a, float b) {
  f16 ha = (f16)a, hb = (f16)b;
  uint16_t ua = __builtin_bit_cast(uint16_t, ha);
  uint16_t ub = __builtin_bit_cast(uint16_t, hb);
  return (uint32_t)ua | ((uint32_t)ub << 16);
}

__device__ __forceinline__ float dot2(uint32_t w, uint32_t h, float acc) {
#if __has_builtin(__builtin_amdgcn_fdot2)
  return __builtin_amdgcn_fdot2(__builtin_bit_cast(f16x2, w),
                                __builtin_bit_cast(f16x2, h), acc, false);
#else
  f16x2 wv = __builtin_bit_cast(f16x2, w), hv = __builtin_bit_cast(f16x2, h);
  return acc + (float)wv[0] * (float)hv[0] + (float)wv[1] * (float)hv[1];
#endif
}

__device__ __forceinline__ float tanhfast(float x) {
  float e = __expf(2.0f * x);   // inf-safe at both ends
#if __has_builtin(__builtin_amdgcn_rcpf)
  return 1.0f - 2.0f * __builtin_amdgcn_rcpf(e + 1.0f);
#else
  return 1.0f - 2.0f / (e + 1.0f);
#endif
}

// ---------------------------------------------------------------------------
// Pack weights (f16x2 pairs):
//  wrecR[(j*16+c)*512 + t] = W_rec[64j+(t&63)][64(t>>6)+2c ..+1],   c<16
//  wrecS quads: uq = (c3*8+j)*512 + t, component q in 0..3
//             = W_rec[64j+(t&63)][64(t>>6)+2*(16+4c3+q) ..+1]
//  winT [k*512 + n] = W_in[n][2k..+1]
//  woutT[k*64  + o] = W_out[o][2k..+1]
// ---------------------------------------------------------------------------
__global__ __launch_bounds__(256) void pack_w(
    const float* __restrict__ Wrec, const float* __restrict__ Win,
    const float* __restrict__ Wout, uint32_t* __restrict__ wrecR,
    uint32_t* __restrict__ wrecS, uint32_t* __restrict__ winT,
    uint32_t* __restrict__ woutT) {
  int id = blockIdx.x * 256 + threadIdx.x;
  if (id < R_DW) {
    int t = id & 511, cj = id >> 9;
    int j = cj >> 4, c = cj & 15;
    int row = 64 * j + (t & 63), col = 64 * (t >> 6) + 2 * c;
    const float* s = Wrec + row * 512 + col;
    wrecR[id] = pkf16(s[0], s[1]);
  } else if (id < S_END) {
    int e = id - R_DW;
    int q = e & 3, i4 = e >> 2;
    int t = i4 & 511, cj = i4 >> 9;
    int c3 = cj >> 3, j = cj & 7;
    int row = 64 * j + (t & 63), col = 64 * (t >> 6) + 2 * (CV + 4 * c3 + q);
    const float* s = Wrec + row * 512 + col;
    wrecS[e] = pkf16(s[0], s[1]);
  } else if (id < WIN_END) {
    int e = id - S_END;
    int n = e >> 6, k = e & 63;
    const float* s = Win + n * 128 + 2 * k;
    winT[k * 512 + n] = pkf16(s[0], s[1]);
  } else {
    int e = id - WIN_END;
    int o = e >> 8, k = e & 255;
    const float* s = Wout + o * 512 + 2 * k;
    woutT[k * 64 + o] = pkf16(s[0], s[1]);
  }
}

// ---------------------------------------------------------------------------
// x_proj: xp[m, n] = sum_i inputs[m, i] * W_in[n, i]   (m = b*T+ts, f16 out)
// ---------------------------------------------------------------------------
__global__ __launch_bounds__(512) void xproj_k(
    const float* __restrict__ in, const uint32_t* __restrict__ winT,
    f16* __restrict__ xp) {
  __shared__ uint32_t A[32][64];
  const int t = threadIdx.x;
  const int m0 = blockIdx.x * 32;
#pragma unroll
  for (int i = 0; i < 4; i++) {
    int id = i * 512 + t;
    int r = id >> 6, k = id & 63;
    const float* s = in + (m0 + r) * I_ + 2 * k;
    A[r][k] = pkf16(s[0], s[1]);
  }
  uint32_t w[64];
#pragma unroll
  for (int k = 0; k < 64; k++) w[k] = winT[k * 512 + t];
  __syncthreads();
  for (int r = 0; r < 32; r++) {
    float a0 = 0.f, a1 = 0.f, a2 = 0.f, a3 = 0.f;
#pragma unroll
    for (int k4 = 0; k4 < 16; k4++) {
      uint4 hq = *((const uint4*)&A[r][k4 * 4]);
      a0 = dot2(w[4 * k4 + 0], hq.x, a0);
      a1 = dot2(w[4 * k4 + 1], hq.y, a1);
      a2 = dot2(w[4 * k4 + 2], hq.z, a2);
      a3 = dot2(w[4 * k4 + 3], hq.w, a3);
    }
    xp[(m0 + r) * H_ + t] = (f16)((a0 + a1) + (a2 + a3));
  }
}

// ---------------------------------------------------------------------------
// Recurrence, K-split, register-disciplined (target <= ~230 VGPRs):
//   wr[8][16] = 128 resident weight regs
//   4 streamed chunks of 8 dwordx4 from L2 (sva/svb double-buffer, 32+32)
//   per wave: 8 uniform LDS h-quads/step; partials via pld[8][512]
//   2 lgkm-only barriers/step (vm stays in flight across them)
// ---------------------------------------------------------------------------
__global__ __attribute__((amdgpu_flat_work_group_size(512, 512),
                          amdgpu_waves_per_eu(2, 2)))
void rnn_k(const uint32_t* __restrict__ wrecR, const uint4* __restrict__ wrecS,
           const f16* __restrict__ xp, const float* __restrict__ bias,
           const float* __restrict__ h0, f16* __restrict__ hall,
           float* __restrict__ hfin) {
  __shared__ uint32_t hbuf[512];   // 2 x 256 f16x2 pairs (double-buffered h)
  __shared__ float pld[8 * 512];   // partials [slice][row], 16 KB
  const int b = blockIdx.x, t = threadIdx.x;
  const int l = t & 63, wv = t >> 6;

  uint32_t wr[8][CV];  // 128 resident weight pairs
#pragma unroll
  for (int j = 0; j < 8; j++)
#pragma unroll
    for (int c = 0; c < CV; c++) wr[j][c] = wrecR[((j << 4) + c) * 512 + t];

  float hv = h0[b * H_ + t];
  const float bia = bias[t];
  ((f16*)hbuf)[t] = (f16)hv;

  const f16* xpp = xp + b * (T_ * H_) + t;
  f16* hap = hall + b * H_ + t;
  float xv = (float)xpp[0];
  float* pw = &pld[(wv << 9) + l];   // partial-write base (conflict-free)
  const float* pr = &pld[t];         // reduce-read base  (conflict-free)
  __syncthreads();

  for (int ts = 0; ts < T_; ++ts) {
    const uint32_t* hb = hbuf + ((ts & 1) << 8) + (wv << 5);
    // ---- issue streamed chunks 0,1 (16 x dwordx4, L2-resident data) ----
    uint4 sva[8], svb[8];
#pragma unroll
    for (int j = 0; j < 8; j++) sva[j] = wrecS[(0 * 8 + j) * 512 + t];
#pragma unroll
    for (int j = 0; j < 8; j++) svb[j] = wrecS[(1 * 8 + j) * 512 + t];
    float acc[8];
#pragma unroll
    for (int j = 0; j < 8; j++) acc[j] = 0.f;
    // ---- resident compute: h quads 0..3 (uniform LDS broadcast) ----
#pragma unroll
    for (int q = 0; q < 4; q++) {
      uint4 hq = *((const uint4*)(hb + 4 * q));
#pragma unroll
      for (int j = 0; j < 8; j++) {
        acc[j] = dot2(wr[j][4 * q + 0], hq.x, acc[j]);
        acc[j] = dot2(wr[j][4 * q + 1], hq.y, acc[j]);
        acc[j] = dot2(wr[j][4 * q + 2], hq.z, acc[j]);
        acc[j] = dot2(wr[j][4 * q + 3], hq.w, acc[j]);
      }
    }
    // ---- chunk0 (h quad 4), then refill sva with chunk2 ----
    {
      uint4 hq = *((const uint4*)(hb + 16));
#pragma unroll
      for (int j = 0; j < 8; j++) {
        acc[j] = dot2(sva[j].x, hq.x, acc[j]);
        acc[j] = dot2(sva[j].y, hq.y, acc[j]);
        acc[j] = dot2(sva[j].z, hq.z, acc[j]);
        acc[j] = dot2(sva[j].w, hq.w, acc[j]);
      }
    }
#pragma unroll
    for (int j = 0; j < 8; j++) sva[j] = wrecS[(2 * 8 + j) * 512 + t];
    // ---- chunk1 (h quad 5), then refill svb with chunk3 ----
    {
      uint4 hq = *((const uint4*)(hb + 20));
#pragma unroll
      for (int j = 0; j < 8; j++) {
        acc[j] = dot2(svb[j].x, hq.x, acc[j]);
        acc[j] = dot2(svb[j].y, hq.y, acc[j]);
        acc[j] = dot2(svb[j].z, hq.z, acc[j]);
        acc[j] = dot2(svb[j].w, hq.w, acc[j]);
      }
    }
#pragma unroll
    for (int j = 0; j < 8; j++) svb[j] = wrecS[(3 * 8 + j) * 512 + t];
    // ---- chunk2 (h quad 6) ----
    {
      uint4 hq = *((const uint4*)(hb + 24));
#pragma unroll
      for (int j = 0; j < 8; j++) {
        acc[j] = dot2(sva[j].x, hq.x, acc[j]);
        acc[j] = dot2(sva[j].y, hq.y, acc[j]);
        acc[j] = dot2(sva[j].z, hq.z, acc[j]);
        acc[j] = dot2(sva[j].w, hq.w, acc[j]);
      }
    }
    // ---- chunk3 (h quad 7) ----
    {
      uint4 hq = *((const uint4*)(hb + 28));
#pragma unroll
      for (int j = 0; j < 8; j++) {
        acc[j] = dot2(svb[j].x, hq.x, acc[j]);
        acc[j] = dot2(svb[j].y, hq.y, acc[j]);
        acc[j] = dot2(svb[j].z, hq.z, acc[j]);
        acc[j] = dot2(svb[j].w, hq.w, acc[j]);
      }
    }
    // ---- partial writes (conflict-free: consecutive lanes/banks) ----
#pragma unroll
    for (int j = 0; j < 8; j++) pw[j << 6] = acc[j];
    // xp prefetch for next step (vm, rides across barriers)
    float xn = 0.f;
    if (ts + 1 < T_) xn = (float)xpp[(ts + 1) * H_];
    asm volatile("s_waitcnt lgkmcnt(0)" ::: "memory");
    __builtin_amdgcn_s_barrier();
    asm volatile("" ::: "memory");
    // ---- reduce: thread t owns row t ----
    float sum = 0.f;
#pragma unroll
    for (int w8 = 0; w8 < 8; w8++) sum += pr[w8 << 9];
    float pre = sum + bia + xv;
    hv = (1.0f - ALPHA_) * hv + ALPHA_ * tanhfast(pre);
    f16 hh = (f16)hv;
    ((f16*)hbuf)[(((ts + 1) & 1) << 9) + t] = hh;
    hap[ts * (B_ * H_)] = hh;
    xv = xn;
    asm volatile("s_waitcnt lgkmcnt(0)" ::: "memory");
    __builtin_amdgcn_s_barrier();
    asm volatile("" ::: "memory");
  }
  hfin[b * H_ + t] = hv;
}

// ---------------------------------------------------------------------------
// out[b, ts, o] = sum_h hall[ts][b][h] * W_out[o, h] + b_out[o]
// ---------------------------------------------------------------------------
__global__ __launch_bounds__(256) void outgemm_k(
    const f16* __restrict__ hall, const uint32_t* __restrict__ woutT,
    const float* __restrict__ bout, float* __restrict__ out) {
  __shared__ uint32_t A[32][256];
  const int bid = blockIdx.x;
  const int b = bid >> 4, ts0 = (bid & 15) * 32;
  const int t = threadIdx.x, o = t & 63, g = t >> 6;
  const uint32_t* hp = (const uint32_t*)hall;
#pragma unroll
  for (int i = 0; i < 32; i++) {
    int id = i * 256 + t;
    int r = id >> 8, k = id & 255;
    A[r][k] = hp[(ts0 + r) * (B_ * H_ / 2) + b * (H_ / 2) + k];
  }
  const float bo = bout[o];
  __syncthreads();
  float acc[8];
#pragma unroll
  for (int r = 0; r < 8; r++) acc[r] = 0.f;
  for (int k4 = 0; k4 < 64; k4++) {
    uint32_t w0 = woutT[(4 * k4 + 0) * 64 + o];
    uint32_t w1 = woutT[(4 * k4 + 1) * 64 + o];
    uint32_t w2 = woutT[(4 * k4 + 2) * 64 + o];
    uint32_t w3 = woutT[(4 * k4 + 3) * 64 + o];
#pragma unroll
    for (int r = 0; r < 8; r++) {
      uint4 hq = *((const uint4*)&A[g * 8 + r][k4 * 4]);
      acc[r] = dot2(w0, hq.x, acc[r]);
      acc[r] = dot2(w1, hq.y, acc[r]);
      acc[r] = dot2(w2, hq.z, acc[r]);
      acc[r] = dot2(w3, hq.w, acc[r]);
    }
  }
#pragma unroll
  for (int r = 0; r < 8; r++)
    out[(b * T_ + ts0 + g * 8 + r) * O_ + o] = acc[r] + bo;
}

extern "C" void kernel_launch(void* const* d_in, const int* in_sizes, int n_in,
                              void* d_out, int out_size, void* d_ws,
                              size_t ws_size, hipStream_t stream) {
  const float* inputs = (const float*)d_in[0];  // [B,T,I]
  const float* h0     = (const float*)d_in[1];  // [B,H]
  const float* Win    = (const float*)d_in[2];  // [H,I]
  const float* Wrec   = (const float*)d_in[3];  // [H,H]
  const float* bias   = (const float*)d_in[4];  // [H]
  const float* Wout   = (const float*)d_in[5];  // [O,H]
  const float* bout   = (const float*)d_in[6];  // [O]
  float* out = (float*)d_out;                   // [B,T,O] then [B,H]

  uint8_t* ws = (uint8_t*)d_ws;
  uint32_t* wrecR = (uint32_t*)(ws);                      // 256 KB
  uint32_t* wrecS = (uint32_t*)(ws + (256u << 10));       // 256 KB
  uint32_t* winT  = (uint32_t*)(ws + (512u << 10));       // 128 KB
  uint32_t* woutT = (uint32_t*)(ws + (640u << 10));       //  64 KB
  f16* xp   = (f16*)(ws + (1u << 20));                    //  32 MB [B,T,H]
  f16* hall = (f16*)(ws + (1u << 20) + (32u << 20));      //  32 MB [T,B,H]

  hipLaunchKernelGGL(pack_w, dim3(704), dim3(256), 0, stream, Wrec, Win, Wout,
                     wrecR, wrecS, winT, woutT);
  hipLaunchKernelGGL(xproj_k, dim3(32768 / 32), dim3(512), 0, stream, inputs,
                     winT, xp);
  hipLaunchKernelGGL(rnn_k, dim3(B_), dim3(512), 0, stream, wrecR,
                     (const uint4*)wrecS, xp, bias, h0, hall,
                     out + B_ * T_ * O_);
  hipLaunchKernelGGL(outgemm_k, dim3(B_ * (T_ / 32)), dim3(256), 0, stream,
                     hall, woutT, bout, out);
}